// Round 7
// baseline (249.367 us; speedup 1.0000x reference)
//
#include <hip/hip_runtime.h>
#include <stdint.h>

// ---------------------------------------------------------------------------
// B=4, T=1024, C=1024, H=16, hs=64.
// y = samples @ V (straight-through => forward output IS the Bernoulli sample),
// att_sum = per-row sample count, att_var == 0 exactly.
// Samples reproduce JAX partitionable threefry bit-exactly:
//   bits[i] = o0 ^ o1 of threefry(fold_in(key(0),42), (0, i)).
// Attention: STRIP-PER-WAVE, barrier-free. 1024 blocks x 4 waves; block j owns
// strips {j, 63-j, 31-j, 32+j} (const sum); wave role rotated by (w+(j>>2))&3
// so every SIMD gets all four roles -> per-SIMD load uniform regardless of the
// (undefined) block->CU map. 4 waves/SIMD resident hides threefry dep chains.
// ---------------------------------------------------------------------------

#define T_SEQ 1024
#define QKV_LD 3072

typedef __attribute__((ext_vector_type(8))) short bf16x8;
typedef __attribute__((ext_vector_type(4))) float f32x4;
typedef __attribute__((ext_vector_type(4))) unsigned int u32x4;

typedef __attribute__((address_space(3))) uint32_t lds_u32;
typedef __attribute__((address_space(1))) const uint32_t g_u32;

#define ROTL(x, d) __builtin_amdgcn_alignbit((x), (x), 32 - (d))

__device__ __forceinline__ void threefry2x32(uint32_t k0, uint32_t k1,
                                             uint32_t x0, uint32_t x1,
                                             uint32_t &o0, uint32_t &o1) {
  uint32_t ks2 = k0 ^ k1 ^ 0x1BD11BDAu;
#define TF_R4(a, b, c, d)                                                      \
  x0 += x1; x1 = ROTL(x1, a); x1 ^= x0;                                        \
  x0 += x1; x1 = ROTL(x1, b); x1 ^= x0;                                        \
  x0 += x1; x1 = ROTL(x1, c); x1 ^= x0;                                        \
  x0 += x1; x1 = ROTL(x1, d); x1 ^= x0;
  x0 += k0; x1 += k1;
  TF_R4(13, 15, 26, 6)
  x0 += k1; x1 += ks2 + 1u;
  TF_R4(17, 29, 16, 24)
  x0 += ks2; x1 += k0 + 2u;
  TF_R4(13, 15, 26, 6)
  x0 += k0; x1 += k1 + 3u;
  TF_R4(17, 29, 16, 24)
  x0 += k1; x1 += ks2 + 4u;
  TF_R4(13, 15, 26, 6)
  x0 += ks2; x1 += k0 + 5u;
  o0 = x0; o1 = x1;
#undef TF_R4
}

__device__ __forceinline__ unsigned short f2bf(float f) {  // RNE
  uint32_t u = __float_as_uint(f);
  u += 0x7FFFu + ((u >> 16) & 1u);
  return (unsigned short)(u >> 16);
}

// ---------------------------------------------------------------------------
// Fused f32->bf16 conversion of x, w_attn, w_proj (outputs contiguous in ws).
// ---------------------------------------------------------------------------
#define N_X4  1048576   // 4M f32 / 4
#define N_WA4 786432    // 3M / 4
#define N_WP4 262144    // 1M / 4

__global__ __launch_bounds__(256) void cvt3_bf16(const float4* __restrict__ x,
                                                 const float4* __restrict__ wa,
                                                 const float4* __restrict__ wp,
                                                 uint2* __restrict__ out) {
  size_t i = (size_t)blockIdx.x * 256 + threadIdx.x;
  const float4* src;
  size_t off;
  if (i < N_X4) { src = x; off = i; }
  else if (i < N_X4 + N_WA4) { src = wa; off = i - N_X4; }
  else { src = wp; off = i - (N_X4 + N_WA4); }
  float4 v = src[off];
  uint2 o;
  o.x = (uint32_t)f2bf(v.x) | ((uint32_t)f2bf(v.y) << 16);
  o.y = (uint32_t)f2bf(v.z) | ((uint32_t)f2bf(v.w) << 16);
  out[i] = o;
}

// ---------------------------------------------------------------------------
// bf16 MFMA GEMM: C[M,N] = A[M,K] @ B[N,K]^T. 128x128 tile, BK=32, 4 waves.
// m97 structure: global_load_lds width-16 into LINEAR LDS [row][32 bf16].
// ---------------------------------------------------------------------------
template <int OUT_BF16>
__global__ __launch_bounds__(256) void gemm_bf16(const unsigned short* __restrict__ A,
                                                 const unsigned short* __restrict__ B,
                                                 void* __restrict__ Cout,
                                                 int M, int N, int K) {
  __shared__ unsigned short As[128 * 32];  // 8 KB, linear
  __shared__ unsigned short Bs[128 * 32];

  const int t = threadIdx.x;
  const int lane = t & 63, w = t >> 6;
  const int g = lane >> 4, lr = lane & 15;
  const int rw = w >> 1, cw = w & 1;
  const int bm = blockIdx.x * 128, bn = blockIdx.y * 128;

  const unsigned short* Ag = A + (size_t)(bm + 32 * w + (lane >> 2)) * K + 8 * (lane & 3);
  const unsigned short* Bg = B + (size_t)(bn + 32 * w + (lane >> 2)) * K + 8 * (lane & 3);
  lds_u32* Al0 = (lds_u32*)&As[(32 * w) * 32];
  lds_u32* Al1 = (lds_u32*)&As[(32 * w + 16) * 32];
  lds_u32* Bl0 = (lds_u32*)&Bs[(32 * w) * 32];
  lds_u32* Bl1 = (lds_u32*)&Bs[(32 * w + 16) * 32];

  f32x4 acc[4][4];
#pragma unroll
  for (int i = 0; i < 4; ++i)
#pragma unroll
    for (int j = 0; j < 4; ++j) acc[i][j] = (f32x4){0.f, 0.f, 0.f, 0.f};

  for (int k0 = 0; k0 < K; k0 += 32) {
    __syncthreads();
    __builtin_amdgcn_global_load_lds((g_u32*)(const void*)(Ag + k0), Al0, 16, 0, 0);
    __builtin_amdgcn_global_load_lds((g_u32*)(const void*)(Ag + k0 + (size_t)16 * K), Al1, 16, 0, 0);
    __builtin_amdgcn_global_load_lds((g_u32*)(const void*)(Bg + k0), Bl0, 16, 0, 0);
    __builtin_amdgcn_global_load_lds((g_u32*)(const void*)(Bg + k0 + (size_t)16 * K), Bl1, 16, 0, 0);
    __syncthreads();

    bf16x8 af[4], bfr[4];
#pragma unroll
    for (int i = 0; i < 4; ++i)
      af[i] = *(const bf16x8*)&As[(64 * rw + 16 * i + lr) * 32 + 8 * g];
#pragma unroll
    for (int j = 0; j < 4; ++j)
      bfr[j] = *(const bf16x8*)&Bs[(64 * cw + 16 * j + lr) * 32 + 8 * g];
#pragma unroll
    for (int i = 0; i < 4; ++i)
#pragma unroll
      for (int j = 0; j < 4; ++j)
        acc[i][j] = __builtin_amdgcn_mfma_f32_16x16x32_bf16(af[i], bfr[j], acc[i][j], 0, 0, 0);
  }

#pragma unroll
  for (int i = 0; i < 4; ++i)
#pragma unroll
    for (int j = 0; j < 4; ++j)
#pragma unroll
      for (int r = 0; r < 4; ++r) {
        const size_t row = bm + 64 * rw + 16 * i + 4 * g + r;
        const size_t col = bn + 64 * cw + 16 * j + lr;
        if (OUT_BF16)
          ((unsigned short*)Cout)[row * N + col] = f2bf(acc[i][j][r]);
        else
          ((float*)Cout)[row * N + col] = acc[i][j][r];
      }
}

// ---------------------------------------------------------------------------
// V pre-transpose: qkv[token][2048 + h*64 + d] -> Vt[(bh*64 + d)*1024 + tok].
// ---------------------------------------------------------------------------
__global__ __launch_bounds__(256) void vtrans(const unsigned short* __restrict__ qkv,
                                              unsigned short* __restrict__ Vt) {
  const int i = blockIdx.x;            // 0..1023
  const int bh = i >> 4, kc = i & 15;  // 64-token chunk kc
  const int b = bh >> 4, h = bh & 15;
  const int t = threadIdx.x;
  const int dr = t & 63, kgrp = t >> 6;

  const unsigned short* src =
      qkv + (size_t)(b * T_SEQ + kc * 64 + kgrp * 16) * QKV_LD + 2048 + h * 64 + dr;
  uint32_t pk[8];
#pragma unroll
  for (int j = 0; j < 8; ++j) {
    uint32_t lo = src[(size_t)(2 * j) * QKV_LD];
    uint32_t hi = src[(size_t)(2 * j + 1) * QKV_LD];
    pk[j] = lo | (hi << 16);
  }
  unsigned short* dst = Vt + ((size_t)bh * 64 + dr) * 1024 + kc * 64 + kgrp * 16;
  *(u32x4*)dst = (u32x4){pk[0], pk[1], pk[2], pk[3]};
  *(u32x4*)(dst + 8) = (u32x4){pk[4], pk[5], pk[6], pk[7]};
}

// ---------------------------------------------------------------------------
// Strip-per-wave MFMA attention + exact threefry Bernoulli sampling.
// 1024 blocks x 256 threads. Block i: bh = XCD-affine, j = i>>6 in [0,16).
// Wave w -> strip via role (w+(j>>2))&3 over {j, 63-j, 31-j, 32+j}.
// No barriers; St wave-private [16][40] bf16 (2-way-free banks).
// ---------------------------------------------------------------------------
__global__ __launch_bounds__(256, 4) void attn_strip(const unsigned short* __restrict__ qkv,
                                                     const unsigned short* __restrict__ Vt,
                                                     unsigned short* __restrict__ yatt,
                                                     float* __restrict__ att_sum,
                                                     float* __restrict__ att_var) {
  __shared__ unsigned short St[4][16][40];

  const int t = threadIdx.x;
  const int lane = t & 63, w = t >> 6;
  const int g = lane >> 4, lr = lane & 15;
  const int i = blockIdx.x;                     // 0..1023
  const int bh = 8 * (i & 7) + ((i >> 3) & 7);  // XCD-affine
  const int j = i >> 6;                         // 0..15
  const int b = bh >> 4, h = bh & 15;

  const int role = (w + (j >> 2)) & 3;
  const int s = (role == 0) ? j : (role == 1) ? 63 - j : (role == 2) ? 31 - j : 32 + j;
  const int q0 = 16 * s;

  uint32_t dk0, dk1;  // fold_in(key(0), 42)
  threefry2x32(0u, 0u, 0u, 42u, dk0, dk1);

  unsigned short (*stw)[40] = St[w];
  const unsigned short* kb = qkv + (size_t)b * T_SEQ * QKV_LD + 1024 + h * 64;
  const unsigned short* vb = Vt + (size_t)bh * 64 * 1024;

  // Q A-frags (constant across k-tiles)
  const unsigned short* qr = qkv + (size_t)(b * T_SEQ + q0 + lr) * QKV_LD + h * 64 + 8 * g;
  const bf16x8 aq0 = *(const bf16x8*)qr;
  const bf16x8 aq1 = *(const bf16x8*)(qr + 32);

  f32x4 yacc[4];
#pragma unroll
  for (int c = 0; c < 4; ++c) yacc[c] = (f32x4){0.f, 0.f, 0.f, 0.f};
  float rs[4] = {0.f, 0.f, 0.f, 0.f};

  const int nk = (q0 + 47) >> 5;  // ceil((q0+16)/32)
  // lane-constant part of the threefry counter: (4g)<<10 | lr
  const uint32_t lane_idx = ((uint32_t)(4 * g) << 10) | (uint32_t)lr;
  const uint32_t base_idx = ((uint32_t)bh << 20) | ((uint32_t)q0 << 10);

#pragma unroll 1
  for (int kt = 0; kt < nk; ++kt) {
    const int kg0 = 32 * kt;
    // K frags for this step (L2-resident; 4 waves/SIMD hide latency)
    bf16x8 cbk[4], cbv[4];
#pragma unroll
    for (int c = 0; c < 2; ++c) {
      const unsigned short* kr = kb + (size_t)(kg0 + 16 * c + lr) * QKV_LD + 8 * g;
      cbk[2 * c] = *(const bf16x8*)kr;
      cbk[2 * c + 1] = *(const bf16x8*)(kr + 32);
    }
#pragma unroll
    for (int c = 0; c < 4; ++c)
      cbv[c] = *(const bf16x8*)(vb + (size_t)(16 * c + lr) * 1024 + kg0 + 8 * g);

    // QK^T (2 column-tiles) + sigmoid + threefry sample
#pragma unroll
    for (int c = 0; c < 2; ++c) {
      f32x4 sa = __builtin_amdgcn_mfma_f32_16x16x32_bf16(aq0, cbk[2 * c],
                                                         (f32x4){0.f, 0.f, 0.f, 0.f}, 0, 0, 0);
      sa = __builtin_amdgcn_mfma_f32_16x16x32_bf16(aq1, cbk[2 * c + 1], sa, 0, 0, 0);
      const int kg = kg0 + 16 * c + lr;
      const uint32_t idx_c = base_idx + (uint32_t)(kg0 + 16 * c) + lane_idx;
#pragma unroll
      for (int r = 0; r < 4; ++r) {
        const int qg = q0 + 4 * g + r;
        float samp = 0.f;
        if (kg <= qg) {
          // p = 1/(1+e), e = exp(-s/8) = exp2(s * -log2(e)/8)
          float e = __builtin_exp2f(sa[r] * -0.18033688011112042f);
          uint32_t r0, r1;
          threefry2x32(dk0, dk1, 0u, idx_c + ((uint32_t)r << 10), r0, r1);
          float u = __uint_as_float(0x3F800000u | ((r0 ^ r1) >> 9)) - 1.0f;
          samp = (fmaf(u, e, u) < 1.0f) ? 1.0f : 0.0f;  // u(1+e) < 1
        }
        rs[r] += samp;
        stw[4 * g + r][16 * c + lr] = (unsigned short)(__float_as_uint(samp) >> 16);
      }
    }

    // PV: A-frag from wave-private St (same-wave dep, no barrier)
    const bf16x8 pa = *(const bf16x8*)&stw[lr][8 * g];
#pragma unroll
    for (int c = 0; c < 4; ++c)
      yacc[c] = __builtin_amdgcn_mfma_f32_16x16x32_bf16(pa, cbv[c], yacc[c], 0, 0, 0);
  }

  // ---- epilogue: yatt (bf16), att_sum, att_var ----
  const size_t yb = (size_t)(b * T_SEQ + q0) * 1024 + h * 64;
#pragma unroll
  for (int c = 0; c < 4; ++c)
#pragma unroll
    for (int r = 0; r < 4; ++r)
      yatt[yb + (size_t)(4 * g + r) * 1024 + 16 * c + lr] = f2bf(yacc[c][r]);

#pragma unroll
  for (int r = 0; r < 4; ++r) {
    rs[r] += __shfl_xor(rs[r], 1);
    rs[r] += __shfl_xor(rs[r], 2);
    rs[r] += __shfl_xor(rs[r], 4);
    rs[r] += __shfl_xor(rs[r], 8);
  }
  if (lr == 0) {
#pragma unroll
    for (int r = 0; r < 4; ++r)
      att_sum[(size_t)bh * T_SEQ + q0 + 4 * g + r] = rs[r];
  }
  if (lane < 16) att_var[(size_t)bh * T_SEQ + q0 + lane] = 0.f;  // s*(1-s)==0
}

extern "C" void kernel_launch(void* const* d_in, const int* in_sizes, int n_in,
                              void* d_out, int out_size, void* d_ws, size_t ws_size,
                              hipStream_t stream) {
  (void)in_sizes; (void)n_in; (void)out_size; (void)ws_size;
  const float* x      = (const float*)d_in[0];  // [4,1024,1024]
  const float* w_attn = (const float*)d_in[1];  // [3072,1024]
  const float* w_proj = (const float*)d_in[2];  // [1024,1024]

  float* y_out      = (float*)d_out;                    // [4,1024,1024] f32
  float* attsum_out = y_out + (size_t)4 * 1024 * 1024;  // [4,16,1024]
  float* attvar_out = attsum_out + (size_t)4 * 16 * 1024;

  unsigned short* ws_us = (unsigned short*)d_ws;
  unsigned short* x_bf    = ws_us;                             // 4M elems
  unsigned short* wa_bf   = x_bf + (size_t)4 * 1024 * 1024;    // 3M
  unsigned short* wp_bf   = wa_bf + (size_t)3 * 1024 * 1024;   // 1M
  unsigned short* qkv_bf  = wp_bf + (size_t)1024 * 1024;       // 12M
  unsigned short* yatt_bf = qkv_bf + (size_t)4096 * 3072;      // 4M
  unsigned short* vt_bf   = yatt_bf + (size_t)4096 * 1024;     // 4M

  dim3 blk(256);
  cvt3_bf16<<<dim3(8192), blk, 0, stream>>>((const float4*)x, (const float4*)w_attn,
                                            (const float4*)w_proj, (uint2*)x_bf);
  gemm_bf16<1><<<dim3(32, 24), blk, 0, stream>>>(x_bf, wa_bf, (void*)qkv_bf, 4096, 3072, 1024);
  vtrans<<<dim3(1024), blk, 0, stream>>>(qkv_bf, vt_bf);
  attn_strip<<<dim3(1024), blk, 0, stream>>>(qkv_bf, vt_bf, yatt_bf, attsum_out, attvar_out);
  gemm_bf16<0><<<dim3(32, 8), blk, 0, stream>>>(yatt_bf, wp_bf, (void*)y_out, 4096, 1024, 1024);
}

// Round 8
// 165.182 us; speedup vs baseline: 1.5097x; 1.5097x over previous
//
#include <hip/hip_runtime.h>
#include <stdint.h>

// ---------------------------------------------------------------------------
// B=4, T=1024, C=1024, H=16, hs=64.
// y = samples @ V (straight-through => forward output IS the Bernoulli sample),
// att_sum = per-row sample count, att_var == 0 exactly.
// Samples reproduce JAX partitionable threefry bit-exactly:
//   bits[i] = o0 ^ o1 of threefry(fold_in(key(0),42), (0, i)).
// Attention: R3 tiled skeleton (LDS-staged K/V, 4 waves, (bh,qt) blocks) with
// 25.6KB LDS (all 1024 blocks resident) and a qt table whose sums are equal
// over the co-residency strata {i, i+256, i+512, i+768} -> per-CU work = 34
// k-steps exactly, mapping-robust.
// ---------------------------------------------------------------------------

#define T_SEQ 1024
#define QKV_LD 3072

typedef __attribute__((ext_vector_type(8))) short bf16x8;
typedef __attribute__((ext_vector_type(4))) float f32x4;
typedef __attribute__((ext_vector_type(4))) unsigned int u32x4;

typedef __attribute__((address_space(3))) uint32_t lds_u32;
typedef __attribute__((address_space(1))) const uint32_t g_u32;

#define ROTL(x, d) __builtin_amdgcn_alignbit((x), (x), 32 - (d))

__device__ __forceinline__ void threefry2x32(uint32_t k0, uint32_t k1,
                                             uint32_t x0, uint32_t x1,
                                             uint32_t &o0, uint32_t &o1) {
  uint32_t ks2 = k0 ^ k1 ^ 0x1BD11BDAu;
#define TF_R4(a, b, c, d)                                                      \
  x0 += x1; x1 = ROTL(x1, a); x1 ^= x0;                                        \
  x0 += x1; x1 = ROTL(x1, b); x1 ^= x0;                                        \
  x0 += x1; x1 = ROTL(x1, c); x1 ^= x0;                                        \
  x0 += x1; x1 = ROTL(x1, d); x1 ^= x0;
  x0 += k0; x1 += k1;
  TF_R4(13, 15, 26, 6)
  x0 += k1; x1 += ks2 + 1u;
  TF_R4(17, 29, 16, 24)
  x0 += ks2; x1 += k0 + 2u;
  TF_R4(13, 15, 26, 6)
  x0 += k0; x1 += k1 + 3u;
  TF_R4(17, 29, 16, 24)
  x0 += k1; x1 += ks2 + 4u;
  TF_R4(13, 15, 26, 6)
  x0 += ks2; x1 += k0 + 5u;
  o0 = x0; o1 = x1;
#undef TF_R4
}

__device__ __forceinline__ unsigned short f2bf(float f) {  // RNE
  uint32_t u = __float_as_uint(f);
  u += 0x7FFFu + ((u >> 16) & 1u);
  return (unsigned short)(u >> 16);
}

// ---------------------------------------------------------------------------
// Fused f32->bf16 conversion of x, w_attn, w_proj (outputs contiguous in ws).
// ---------------------------------------------------------------------------
#define N_X4  1048576   // 4M f32 / 4
#define N_WA4 786432    // 3M / 4
#define N_WP4 262144    // 1M / 4

__global__ __launch_bounds__(256) void cvt3_bf16(const float4* __restrict__ x,
                                                 const float4* __restrict__ wa,
                                                 const float4* __restrict__ wp,
                                                 uint2* __restrict__ out) {
  size_t i = (size_t)blockIdx.x * 256 + threadIdx.x;
  const float4* src;
  size_t off;
  if (i < N_X4) { src = x; off = i; }
  else if (i < N_X4 + N_WA4) { src = wa; off = i - N_X4; }
  else { src = wp; off = i - (N_X4 + N_WA4); }
  float4 v = src[off];
  uint2 o;
  o.x = (uint32_t)f2bf(v.x) | ((uint32_t)f2bf(v.y) << 16);
  o.y = (uint32_t)f2bf(v.z) | ((uint32_t)f2bf(v.w) << 16);
  out[i] = o;
}

// ---------------------------------------------------------------------------
// bf16 MFMA GEMM: C[M,N] = A[M,K] @ B[N,K]^T. 128x128 tile, BK=32, 4 waves.
// m97 structure: global_load_lds width-16 into LINEAR LDS [row][32 bf16].
// ---------------------------------------------------------------------------
template <int OUT_BF16>
__global__ __launch_bounds__(256) void gemm_bf16(const unsigned short* __restrict__ A,
                                                 const unsigned short* __restrict__ B,
                                                 void* __restrict__ Cout,
                                                 int M, int N, int K) {
  __shared__ unsigned short As[128 * 32];  // 8 KB, linear
  __shared__ unsigned short Bs[128 * 32];

  const int t = threadIdx.x;
  const int lane = t & 63, w = t >> 6;
  const int g = lane >> 4, lr = lane & 15;
  const int rw = w >> 1, cw = w & 1;
  const int bm = blockIdx.x * 128, bn = blockIdx.y * 128;

  const unsigned short* Ag = A + (size_t)(bm + 32 * w + (lane >> 2)) * K + 8 * (lane & 3);
  const unsigned short* Bg = B + (size_t)(bn + 32 * w + (lane >> 2)) * K + 8 * (lane & 3);
  lds_u32* Al0 = (lds_u32*)&As[(32 * w) * 32];
  lds_u32* Al1 = (lds_u32*)&As[(32 * w + 16) * 32];
  lds_u32* Bl0 = (lds_u32*)&Bs[(32 * w) * 32];
  lds_u32* Bl1 = (lds_u32*)&Bs[(32 * w + 16) * 32];

  f32x4 acc[4][4];
#pragma unroll
  for (int i = 0; i < 4; ++i)
#pragma unroll
    for (int j = 0; j < 4; ++j) acc[i][j] = (f32x4){0.f, 0.f, 0.f, 0.f};

  for (int k0 = 0; k0 < K; k0 += 32) {
    __syncthreads();
    __builtin_amdgcn_global_load_lds((g_u32*)(const void*)(Ag + k0), Al0, 16, 0, 0);
    __builtin_amdgcn_global_load_lds((g_u32*)(const void*)(Ag + k0 + (size_t)16 * K), Al1, 16, 0, 0);
    __builtin_amdgcn_global_load_lds((g_u32*)(const void*)(Bg + k0), Bl0, 16, 0, 0);
    __builtin_amdgcn_global_load_lds((g_u32*)(const void*)(Bg + k0 + (size_t)16 * K), Bl1, 16, 0, 0);
    __syncthreads();

    bf16x8 af[4], bfr[4];
#pragma unroll
    for (int i = 0; i < 4; ++i)
      af[i] = *(const bf16x8*)&As[(64 * rw + 16 * i + lr) * 32 + 8 * g];
#pragma unroll
    for (int j = 0; j < 4; ++j)
      bfr[j] = *(const bf16x8*)&Bs[(64 * cw + 16 * j + lr) * 32 + 8 * g];
#pragma unroll
    for (int i = 0; i < 4; ++i)
#pragma unroll
      for (int j = 0; j < 4; ++j)
        acc[i][j] = __builtin_amdgcn_mfma_f32_16x16x32_bf16(af[i], bfr[j], acc[i][j], 0, 0, 0);
  }

#pragma unroll
  for (int i = 0; i < 4; ++i)
#pragma unroll
    for (int j = 0; j < 4; ++j)
#pragma unroll
      for (int r = 0; r < 4; ++r) {
        const size_t row = bm + 64 * rw + 16 * i + 4 * g + r;
        const size_t col = bn + 64 * cw + 16 * j + lr;
        if (OUT_BF16)
          ((unsigned short*)Cout)[row * N + col] = f2bf(acc[i][j][r]);
        else
          ((float*)Cout)[row * N + col] = acc[i][j][r];
      }
}

// ---------------------------------------------------------------------------
// Tiled MFMA attention + exact threefry Bernoulli sampling.
// Block = (bh, qt); 1024 blocks x 4 waves; LDS 25.6KB -> ALL blocks resident.
// Co-residency strata {c, c+4, c+8, c+12} of QT2 each sum to 30 -> per-CU
// work = 34 k-steps exactly. Q frags direct from global; samples stored as
// bf16 ushort in wave-private St[16][72] (write 2-way-free, read uniform).
// ---------------------------------------------------------------------------
__constant__ int QT2[16] = {15, 13, 11, 9, 0, 2, 4, 6, 14, 12, 10, 8, 1, 3, 5, 7};

__global__ __launch_bounds__(256) void attn_tile2(const unsigned short* __restrict__ qkv,
                                                  unsigned short* __restrict__ yatt,
                                                  float* __restrict__ att_sum,
                                                  float* __restrict__ att_var) {
  __shared__ uint32_t Ks4[64 * 32];            // 8 KB
  __shared__ uint32_t Vt4[64 * 32];            // 8 KB
  __shared__ unsigned short St[4][16][72];     // 9.2 KB, wave-private strips

  const int t = threadIdx.x;
  const int lane = t & 63, w = t >> 6;
  const int g = lane >> 4, lr = lane & 15;
  const int i = blockIdx.x;                     // 0..1023
  const int bh = 8 * (i & 7) + ((i >> 3) & 7);  // XCD-affine
  const int qt = QT2[i >> 6];
  const int b = bh >> 4, h = bh & 15;
  const int qt64 = qt * 64;

  uint32_t dk0, dk1;  // fold_in(key(0), 42)
  threefry2x32(0u, 0u, 0u, 42u, dk0, dk1);

  const int swzr = (lr & 7) << 2;
  unsigned short (*stw)[72] = St[w];

  // ---- Q A-frags direct from global (row q0+lr, 16B x 2 halves) ----
  const int q0 = qt64 + 16 * w;
  const unsigned short* qr = qkv + (size_t)(b * T_SEQ + q0 + lr) * QKV_LD + h * 64 + 8 * g;
  const bf16x8 aq0 = *(const bf16x8*)qr;
  const bf16x8 aq1 = *(const bf16x8*)(qr + 32);

  f32x4 yacc[4];
#pragma unroll
  for (int c = 0; c < 4; ++c) yacc[c] = (f32x4){0.f, 0.f, 0.f, 0.f};
  int rs[4] = {0, 0, 0, 0};

#pragma unroll 1
  for (int kt = 0; kt <= qt; ++kt) {
    __syncthreads();  // prev Ks/Vt reads complete
    // ---- stage K tile (coalesced, swizzled) ----
    const unsigned short* kb = qkv + (size_t)(b * T_SEQ + kt * 64) * QKV_LD + 1024 + h * 64;
    {
      const int r = t >> 2, s4 = t & 3;
      const unsigned short* src = kb + (size_t)r * QKV_LD + 8 * s4;
      u32x4 v0 = *(const u32x4*)(src);
      u32x4 v1 = *(const u32x4*)(src + 32);
      const int sw = (r & 7) << 2;
      *(u32x4*)&Ks4[r * 32 + ((4 * s4) ^ sw)] = v0;
      *(u32x4*)&Ks4[r * 32 + ((4 * s4 + 16) ^ sw)] = v1;
    }
    // ---- stage V transposed: Vt[d][k] ----
    {
      const int k2 = 2 * (t & 31), d0 = 8 * (t >> 5);
      const unsigned short* vsrc =
          qkv + (size_t)(b * T_SEQ + kt * 64 + k2) * QKV_LD + 2048 + h * 64 + d0;
      union { u32x4 v; unsigned short us[8]; } va, vb;
      va.v = *(const u32x4*)(vsrc);
      vb.v = *(const u32x4*)(vsrc + QKV_LD);
#pragma unroll
      for (int j = 0; j < 8; ++j) {
        uint32_t pw = (uint32_t)va.us[j] | ((uint32_t)vb.us[j] << 16);
        Vt4[(d0 + j) * 32 + ((t & 31) ^ ((j & 7) << 2))] = pw;
      }
    }
    __syncthreads();

    // ---- QK^T + sigmoid + threefry sample ----
    const int kt64 = kt * 64;
#pragma unroll
    for (int c = 0; c < 4; ++c) {
      const uint32_t* krow = &Ks4[(16 * c + lr) * 32];
      bf16x8 bk0 = *(const bf16x8*)&krow[(4 * g) ^ swzr];
      bf16x8 bk1 = *(const bf16x8*)&krow[(4 * g + 16) ^ swzr];
      f32x4 sa = __builtin_amdgcn_mfma_f32_16x16x32_bf16(aq0, bk0, (f32x4){0.f, 0.f, 0.f, 0.f}, 0, 0, 0);
      sa = __builtin_amdgcn_mfma_f32_16x16x32_bf16(aq1, bk1, sa, 0, 0, 0);

      const int kg = kt64 + 16 * c + lr;
#pragma unroll
      for (int r = 0; r < 4; ++r) {
        const int qg = q0 + 4 * g + r;
        unsigned short sbits = 0;
        if (kg <= qg) {
          // p = 1/(1+e), e = exp(-s/8) = exp2(s * -log2(e)/8)
          float e = __builtin_exp2f(sa[r] * -0.18033688011112042f);
          uint32_t idx = ((uint32_t)bh << 20) | ((uint32_t)qg << 10) | (uint32_t)kg;
          uint32_t r0, r1;
          threefry2x32(dk0, dk1, 0u, idx, r0, r1);
          float u = __uint_as_float(0x3F800000u | ((r0 ^ r1) >> 9)) - 1.0f;
          if (fmaf(u, e, u) < 1.0f) { sbits = 0x3F80; rs[r] += 1; }  // u(1+e)<1
        }
        stw[4 * g + r][16 * c + lr] = sbits;
      }
    }
    // St rows are wave-private: same-wave LDS dep, no barrier.

    // ---- Y += P @ V ----
#pragma unroll
    for (int ks = 0; ks < 2; ++ks) {
      const bf16x8 pa = *(const bf16x8*)&stw[lr][32 * ks + 8 * g];
#pragma unroll
      for (int c = 0; c < 4; ++c) {
        bf16x8 vb = *(const bf16x8*)&Vt4[(16 * c + lr) * 32 + ((4 * g + 16 * ks) ^ swzr)];
        yacc[c] = __builtin_amdgcn_mfma_f32_16x16x32_bf16(pa, vb, yacc[c], 0, 0, 0);
      }
    }
  }

  // ---- epilogue: yatt (bf16), att_sum, att_var ----
  const size_t yb = (size_t)(b * T_SEQ + q0) * 1024 + h * 64;
#pragma unroll
  for (int c = 0; c < 4; ++c)
#pragma unroll
    for (int r = 0; r < 4; ++r)
      yatt[yb + (size_t)(4 * g + r) * 1024 + 16 * c + lr] = f2bf(yacc[c][r]);

#pragma unroll
  for (int r = 0; r < 4; ++r) {
    rs[r] += __shfl_xor(rs[r], 1);
    rs[r] += __shfl_xor(rs[r], 2);
    rs[r] += __shfl_xor(rs[r], 4);
    rs[r] += __shfl_xor(rs[r], 8);
  }
  if (lr == 0) {
#pragma unroll
    for (int r = 0; r < 4; ++r)
      att_sum[(size_t)bh * T_SEQ + q0 + 4 * g + r] = (float)rs[r];
  }
  if (lane < 16) att_var[(size_t)bh * T_SEQ + qt64 + 16 * w + lane] = 0.f;  // s*(1-s)==0
}

extern "C" void kernel_launch(void* const* d_in, const int* in_sizes, int n_in,
                              void* d_out, int out_size, void* d_ws, size_t ws_size,
                              hipStream_t stream) {
  (void)in_sizes; (void)n_in; (void)out_size; (void)ws_size;
  const float* x      = (const float*)d_in[0];  // [4,1024,1024]
  const float* w_attn = (const float*)d_in[1];  // [3072,1024]
  const float* w_proj = (const float*)d_in[2];  // [1024,1024]

  float* y_out      = (float*)d_out;                    // [4,1024,1024] f32
  float* attsum_out = y_out + (size_t)4 * 1024 * 1024;  // [4,16,1024]
  float* attvar_out = attsum_out + (size_t)4 * 16 * 1024;

  unsigned short* ws_us = (unsigned short*)d_ws;
  unsigned short* x_bf    = ws_us;                             // 4M elems
  unsigned short* wa_bf   = x_bf + (size_t)4 * 1024 * 1024;    // 3M
  unsigned short* wp_bf   = wa_bf + (size_t)3 * 1024 * 1024;   // 1M
  unsigned short* qkv_bf  = wp_bf + (size_t)1024 * 1024;       // 12M
  unsigned short* yatt_bf = qkv_bf + (size_t)4096 * 3072;      // 4M

  dim3 blk(256);
  cvt3_bf16<<<dim3(8192), blk, 0, stream>>>((const float4*)x, (const float4*)w_attn,
                                            (const float4*)w_proj, (uint2*)x_bf);
  gemm_bf16<1><<<dim3(32, 24), blk, 0, stream>>>(x_bf, wa_bf, (void*)qkv_bf, 4096, 3072, 1024);
  attn_tile2<<<dim3(1024), blk, 0, stream>>>(qkv_bf, yatt_bf, attsum_out, attvar_out);
  gemm_bf16<0><<<dim3(32, 8), blk, 0, stream>>>(yatt_bf, wp_bf, (void*)y_out, 4096, 1024, 1024);
}